// Round 14
// baseline (228.189 us; speedup 1.0000x reference)
//
#include <hip/hip_runtime.h>
#include <cstdint>
#include <cstddef>

// ---------------------------------------------------------------------------
// RPN_11562051961518 — r14: conv frozen at r13 optimum (256px x 128oc, ratio
// 2.67, 2 blk/CU, 167us / 925 TF). Tail consolidation: prep merged into one
// kernel (7 launches total), heads retiled to 256px/block with exact XCD
// affinity. Labels pipeline unchanged (bit-exact).
// ---------------------------------------------------------------------------

#define A_TOT 36864

typedef unsigned short ushortT;
typedef __attribute__((ext_vector_type(8))) short short8;
typedef __attribute__((ext_vector_type(4))) float f32x4;

typedef __attribute__((address_space(1))) unsigned char gbyte_t;
typedef __attribute__((address_space(3))) unsigned char lbyte_t;

__device__ __forceinline__ void gld_lds16(const void* g, void* l) {
  __builtin_amdgcn_global_load_lds((gbyte_t*)g, (lbyte_t*)l, 16, 0, 0);
}

__device__ __forceinline__ uint32_t rotl32(uint32_t v, int d) { return (v << d) | (v >> (32 - d)); }

__device__ __forceinline__ ushortT f2bf(float f) {
  uint32_t u = __float_as_uint(f);
  uint32_t r = (u + 0x7FFFu + ((u >> 16) & 1u)) >> 16;   // RNE
  return (ushortT)r;
}

__device__ __forceinline__ uint32_t f2mono(float f) {
  uint32_t b = __float_as_uint(f);
  return b ^ ((b >> 31) ? 0xFFFFFFFFu : 0x80000000u);
}
__device__ __forceinline__ float mono2f(uint32_t u) {
  uint32_t b = (u >> 31) ? (u ^ 0x80000000u) : ~u;
  return __uint_as_float(b);
}

// JAX threefry2x32, key=(0,42), partitionable: counter (0, i), out = x0^x1.
__device__ uint32_t threefry_bits_for(uint32_t a) {
  uint32_t x0 = 0u, x1 = a;
  const uint32_t k0 = 0u, k1 = 42u;
  const uint32_t k2 = k0 ^ k1 ^ 0x1BD11BDAu;
  x0 += k0; x1 += k1;
#define TF_RND(r) { x0 += x1; x1 = rotl32(x1, (r)); x1 ^= x0; }
  TF_RND(13) TF_RND(15) TF_RND(26) TF_RND(6)
  x0 += k1; x1 += k2 + 1u;
  TF_RND(17) TF_RND(29) TF_RND(16) TF_RND(24)
  x0 += k2; x1 += k0 + 2u;
  TF_RND(13) TF_RND(15) TF_RND(26) TF_RND(6)
  x0 += k0; x1 += k1 + 3u;
  TF_RND(17) TF_RND(29) TF_RND(16) TF_RND(24)
  x0 += k1; x1 += k2 + 4u;
  TF_RND(13) TF_RND(15) TF_RND(26) TF_RND(6)
  x0 += k2; x1 += k0 + 5u;
#undef TF_RND
  return x0 ^ x1;
}

struct Anc { float x1, y1, x2, y2; bool inside; };

__device__ __forceinline__ Anc anchor_at(int a, float iw, float ih) {
  Anc A;
  {
    #pragma clang fp contract(off)
    int p = a / 9;
    int q = a - p * 9;
    int i = p >> 6;
    int j = p & 63;
    int ri = q / 3;
    int si = q - ri * 3;
    const float ratios[3] = {0.5f, 1.0f, 2.0f};
    const float scales[3] = {8.0f, 16.0f, 32.0f};
    float xs = iw / 64.0f;
    float ys = ih / 64.0f;
    float cx = ((float)i + 0.5f) * xs;
    float cy = ((float)j + 0.5f) * ys;
    float r = ratios[ri], s = scales[si];
    float h = sqrtf((s * s) / r) * ys;
    float w = h * r * xs / ys;
    A.x1 = cx - w * 0.5f;
    A.y1 = cy - h * 0.5f;
    A.x2 = cx + w * 0.5f;
    A.y2 = cy + h * 0.5f;
    A.inside = (A.x1 >= 0.0f) && (A.y1 >= 0.0f) && (A.x2 <= iw) && (A.y2 <= ih);
  }
  return A;
}

__device__ __forceinline__ float iou_one(const Anc& A, const float* g) {
  #pragma clang fp contract(off)
  float x1 = fmaxf(A.x1, g[0]);
  float y1 = fmaxf(A.y1, g[1]);
  float x2 = fminf(A.x2, g[2]);
  float y2 = fminf(A.y2, g[3]);
  float inter = fmaxf(x2 - x1, 0.0f) * fmaxf(y2 - y1, 0.0f);
  float area_a = (A.x2 - A.x1) * (A.y2 - A.y1);
  float area_g = (g[2] - g[0]) * (g[3] - g[1]);
  float un = (area_a + area_g) - inter;
  return inter > 0.0f ? (inter / un) : 0.0f;
}

// --------------------------- labels pipeline ---------------------------
__global__ __launch_bounds__(256) void labels_gtmax_kernel(
    const float* __restrict__ gtr, const int* __restrict__ pih, const int* __restrict__ piw,
    uint32_t* __restrict__ gtbest_bits) {
  __shared__ float s_gt[6][4];
  __shared__ float s_red[4][6];
  int tid = threadIdx.x;
  if (tid < 24) ((float*)s_gt)[tid] = gtr[8 + tid];
  __syncthreads();
  float iw = (float)piw[0], ih = (float)pih[0];
  int a = blockIdx.x * 256 + tid;
  Anc A = anchor_at(a, iw, ih);
  int w = tid >> 6;
  #pragma unroll
  for (int g = 0; g < 6; ++g) {
    float v = A.inside ? iou_one(A, s_gt[g]) : -1.0f;
    for (int off = 32; off > 0; off >>= 1) v = fmaxf(v, __shfl_down(v, off, 64));
    if ((tid & 63) == 0) s_red[w][g] = v;
  }
  __syncthreads();
  if (tid < 6) {
    float m = fmaxf(fmaxf(s_red[0][tid], s_red[1][tid]), fmaxf(s_red[2][tid], s_red[3][tid]));
    atomicMax(&gtbest_bits[tid], f2mono(m));
  }
}

__global__ __launch_bounds__(256) void labels_code_kernel(
    const float* __restrict__ gtr, const int* __restrict__ pih, const int* __restrict__ piw,
    const uint32_t* __restrict__ gtbest_bits, uint32_t* __restrict__ L) {
  __shared__ float s_gt[6][4];
  __shared__ float s_gb[6];
  int tid = threadIdx.x;
  if (tid < 24) ((float*)s_gt)[tid] = gtr[8 + tid];
  if (tid < 6) s_gb[tid] = mono2f(gtbest_bits[tid]);
  __syncthreads();
  float iw = (float)piw[0], ih = (float)pih[0];
  int a = blockIdx.x * 256 + tid;
  Anc A = anchor_at(a, iw, ih);
  uint32_t code;
  if (!A.inside) {
    code = 2u;
  } else {
    float best = -1.0f;
    bool isb = false;
    #pragma unroll
    for (int g = 0; g < 6; ++g) {
      float v = iou_one(A, s_gt[g]);
      best = fmaxf(best, v);
      if (v == s_gb[g] && s_gb[g] > -1.0f) isb = true;
    }
    code = (best >= 0.5f || isb) ? 1u : 0u;
  }
  uint32_t m = threefry_bits_for((uint32_t)a) >> 9;
  L[a] = (m << 2) | code;
}

__global__ __launch_bounds__(1024) void labels_select_kernel(
    const uint32_t* __restrict__ L, unsigned long long* __restrict__ Tsel) {
  __shared__ int hist[2][512];
  __shared__ unsigned long long list[2][512];
  __shared__ int lcnt[2];
  __shared__ int s_b[2], s_r[2];
  int tid = threadIdx.x;
  hist[tid >> 9][tid & 511] = 0;
  if (tid < 2) lcnt[tid] = 0;
  __syncthreads();
  for (int a = tid; a < A_TOT; a += 1024) {
    uint32_t v = L[a];
    uint32_t c = v & 3u;
    if (c < 2u) atomicAdd(&hist[c][v >> 16], 1);
  }
  __syncthreads();
  if (tid < 2) {
    int need = (tid == 1) ? 10 : 22;
    int tot = 0;
    for (int i = 0; i < 512; ++i) tot += hist[tid][i];
    int b = -1, r = 0, cum = 0;
    if (tot > need) {
      for (int i = 0; i < 512; ++i) {
        if (cum + hist[tid][i] >= need) { b = i; r = need - cum; break; }
        cum += hist[tid][i];
      }
    }
    s_b[tid] = b; s_r[tid] = r;
    if (b < 0) Tsel[tid] = ~0ull;
  }
  __syncthreads();
  for (int a = tid; a < A_TOT; a += 1024) {
    uint32_t v = L[a];
    uint32_t c = v & 3u;
    if (c < 2u && s_b[c] == (int)(v >> 16)) {
      int idx = atomicAdd(&lcnt[c], 1);
      if (idx < 512) list[c][idx] = (((unsigned long long)(v >> 2)) << 16) | (unsigned)a;
    }
  }
  __syncthreads();
  #pragma unroll
  for (int c = 0; c < 2; ++c) {
    if (s_b[c] < 0) continue;
    int n = lcnt[c] < 512 ? lcnt[c] : 512;
    if (tid < n) {
      unsigned long long k = list[c][tid];
      int rank = 1;
      for (int i = 0; i < n; ++i) rank += (list[c][i] < k) ? 1 : 0;
      if (rank == s_r[c]) Tsel[c] = k;
    }
  }
}

__global__ __launch_bounds__(256) void labels_final_kernel(
    const uint32_t* __restrict__ L, const unsigned long long* __restrict__ Tsel,
    const float* __restrict__ gtr, const int* __restrict__ pih, const int* __restrict__ piw,
    float* __restrict__ labels_out, float* __restrict__ offs_out) {
  __shared__ float s_gt[6][4];
  int tid = threadIdx.x;
  if (tid < 24) ((float*)s_gt)[tid] = gtr[8 + tid];
  __syncthreads();
  float iw = (float)piw[0], ih = (float)pih[0];
  int a = blockIdx.x * 256 + tid;
  uint32_t v = L[a];
  uint32_t code = v & 3u;
  unsigned long long K = (((unsigned long long)(v >> 2)) << 16) | (unsigned)a;
  bool pos = (code == 1u) && (K <= Tsel[1]);
  bool neg = (code == 0u) && (K <= Tsel[0]);
  labels_out[a] = pos ? 1.0f : (neg ? 0.0f : -1.0f);
  float o0 = 0.0f, o1 = 0.0f, o2 = 0.0f, o3 = 0.0f;
  if (pos) {
    #pragma clang fp contract(off)
    Anc A = anchor_at(a, iw, ih);
    int bi = 0;
    float bv = iou_one(A, s_gt[0]);
    for (int g = 1; g < 6; ++g) {
      float vg = iou_one(A, s_gt[g]);
      if (vg > bv) { bv = vg; bi = g; }
    }
    const float eps = 1.1920928955078125e-07f;
    float wa = fmaxf(A.x2 - A.x1, eps);
    float ha = fmaxf(A.y2 - A.y1, eps);
    float xa = A.x1 + wa * 0.5f;
    float ya = A.y1 + ha * 0.5f;
    const float* g = s_gt[bi];
    float wg = g[2] - g[0];
    float hg = g[3] - g[1];
    float xg = g[0] + wg * 0.5f;
    float yg = g[1] + hg * 0.5f;
    o0 = (xg - xa) / wa;
    o1 = (yg - ya) / ha;
    o2 = logf(wg / wa);
    o3 = logf(hg / ha);
  }
  offs_out[a * 4 + 0] = o0;
  offs_out[a * 4 + 1] = o1;
  offs_out[a * 4 + 2] = o2;
  offs_out[a * 4 + 3] = o3;
}

// --------------------------- merged prep kernel ---------------------------
// grid 8192 x 256:
//  - all blocks: featbf bf16 conversion (idx-th 8-elem chunk) if do_feat
//  - blocks 0..575: coalesced Wt transpose tile (64x64 via LDS)
//  - idx < 73728: Wh; idx < 4096: zrow; idx < 144: bias_all; idx < 6: gtbest
__global__ __launch_bounds__(256) void prep_all_kernel(
    const float* __restrict__ w, const float* __restrict__ feat,
    const float* __restrict__ reg_w, const float* __restrict__ cls_w,
    const float* __restrict__ lmk_w, const float* __restrict__ reg_b,
    const float* __restrict__ cls_b, const float* __restrict__ lmk_b,
    ushortT* __restrict__ Wt, ushortT* __restrict__ featbf,
    ushortT* __restrict__ zrow, ushortT* __restrict__ Wh,
    float* __restrict__ bias_all, uint32_t* __restrict__ gtbest_bits,
    int do_feat) {
  __shared__ float tile[64][65];
  int idx = blockIdx.x * 256 + threadIdx.x;
  if (do_feat) {
    const float4 f0 = *(const float4*)(feat + (size_t)idx * 8);
    const float4 f1 = *(const float4*)(feat + (size_t)idx * 8 + 4);
    short8 o;
    o[0] = (short)f2bf(f0.x); o[1] = (short)f2bf(f0.y);
    o[2] = (short)f2bf(f0.z); o[3] = (short)f2bf(f0.w);
    o[4] = (short)f2bf(f1.x); o[5] = (short)f2bf(f1.y);
    o[6] = (short)f2bf(f1.z); o[7] = (short)f2bf(f1.w);
    *(short8*)(featbf + (size_t)idx * 8) = o;
  }
  if (blockIdx.x < 576) {
    int blk = blockIdx.x;
    int kk = blk / 64;
    int rem = blk - kk * 64;
    int ic0 = (rem >> 3) * 64;
    int oc0 = (rem & 7) * 64;
    int t = threadIdx.x;
    int tr = t >> 6;
    int tc = t & 63;
    #pragma unroll
    for (int r = 0; r < 16; ++r) {
      int ic = tr * 16 + r;
      tile[ic][tc] = w[((size_t)(kk * 512 + ic0 + ic)) * 512 + oc0 + tc];
    }
    __syncthreads();
    #pragma unroll
    for (int r = 0; r < 16; ++r) {
      int oc = tr * 16 + r;
      Wt[((size_t)(kk * 512 + oc0 + oc)) * 512 + ic0 + tc] = f2bf(tile[tc][oc]);
    }
  }
  if (idx < 73728) {
    int c = idx >> 9, ic = idx & 511;
    float v = 0.0f;
    if (c < 72) v = reg_w[ic * 72 + c];
    else if (c < 81) v = cls_w[ic * 9 + (c - 72)];
    else if (c < 135) v = lmk_w[ic * 54 + (c - 81)];
    Wh[idx] = f2bf(v);
  }
  if (do_feat && idx < 4096) {
    *(short8*)(zrow + (size_t)idx * 8) = (short8){0, 0, 0, 0, 0, 0, 0, 0};
  }
  if (idx < 144) {
    float bv = 0.0f;
    if (idx < 72) bv = reg_b[idx];
    else if (idx < 81) bv = cls_b[idx - 72];
    else if (idx < 135) bv = lmk_b[idx - 81];
    bias_all[idx] = bv;
  }
  if (idx < 6) gtbest_bits[idx] = f2mono(-1.0f);
}

// --------------------------- conv3x3 bf16 MFMA (r13, frozen) ---------------------------
__global__ __launch_bounds__(256, 2) void conv3x3_mfma_kernel(
    const ushortT* __restrict__ featbf, const ushortT* __restrict__ zrow,
    const ushortT* __restrict__ Wt, const float* __restrict__ bias,
    ushortT* __restrict__ xbf) {
  __shared__ __align__(16) char Asm[2][16384];   // [buf][4 row-slots][4 grp x 1KB]
  __shared__ __align__(16) char Bsm[2][24576];   // [buf][3 kx][8 oc-frag x 1KB]
  const int tid = threadIdx.x;
  const int lane = tid & 63;
  const int w = tid >> 6;          // wave 0..3 = row slot
  const int kgrp = lane >> 4;
  const int ln15 = lane & 15;

  const int lin = blockIdx.x + 2 * blockIdx.y;
  const int swz = (lin & 7) * 64 + (lin >> 3);
  const int j = swz & 63;
  const int xcd = swz >> 6;
  const int oc0 = (j >> 4) * 128;
  const int mt = xcd * 16 + (j & 15);   // m-tile 0..127
  const int b = mt >> 4;
  const int y0 = (mt & 15) * 4;

  const int bn15 = lane & 15;
  const int bic = ((lane >> 4) & 3) * 8;

  f32x4 acc[4][8];
  #pragma unroll
  for (int i = 0; i < 4; ++i)
    #pragma unroll
    for (int j2 = 0; j2 < 8; ++j2) acc[i][j2] = (f32x4){0.f, 0.f, 0.f, 0.f};
  const short8 zv = (short8){0, 0, 0, 0, 0, 0, 0, 0};

  auto stageA = [&](int t, int bsel) {
    int ic0 = (t / 3) * 32;
    int dy = (t % 3) - 1;
    char* Ab = Asm[bsel];
    #pragma unroll
    for (int i = 0; i < 4; ++i) {
      int c = w + i * 4;
      int s = c >> 2, q = c & 3;
      int ysrc = y0 + s + dy;
      bool vy = (unsigned)ysrc < 64u;
      const ushortT* rowbase = vy ? (featbf + ((size_t)((b * 64 + ysrc) * 64)) * 512) : zrow;
      const ushortT* src = rowbase + (size_t)(q * 16 + bn15) * 512 + ic0 + bic;
      gld_lds16(src, Ab + s * 4096 + q * 1024);
    }
  };
  auto issueB = [&](int t, int bsel) {
    int ic0 = (t / 3) * 32;
    int ky = t % 3;
    char* Bb = Bsm[bsel];
    #pragma unroll
    for (int i = 0; i < 6; ++i) {
      int c = w + i * 4;
      int kxr = c >> 3, cc = c & 7;
      int kk = ky * 3 + kxr;
      int n = cc * 16 + bn15;
      const ushortT* src = Wt + ((size_t)(kk * 512 + oc0 + n)) * 512 + ic0 + bic;
      gld_lds16(src, Bb + kxr * 8192 + cc * 1024);
    }
  };
  auto computeT = [&](int bsel) {
    const char* Ab = Asm[bsel] + w * 4096;
    const char* Bb = Bsm[bsel];
    #pragma unroll
    for (int kx = 0; kx < 3; ++kx) {
      const int dx = kx - 1;
      short8 bfr[8];
      #pragma unroll
      for (int j2 = 0; j2 < 8; ++j2)
        bfr[j2] = *(const short8*)(Bb + kx * 8192 + j2 * 1024 + kgrp * 256 + ln15 * 16);
      short8 afr[4];
      #pragma unroll
      for (int i = 0; i < 4; ++i) {
        int xin = i * 16 + ln15 + dx;
        bool ok = (unsigned)xin < 64u;
        int p = ok ? xin : 0;
        short8 v = *(const short8*)(Ab + (p >> 4) * 1024 + kgrp * 256 + (p & 15) * 16);
        afr[i] = ok ? v : zv;
      }
      #pragma unroll
      for (int i = 0; i < 4; ++i)
        #pragma unroll
        for (int j2 = 0; j2 < 8; ++j2)
          acc[i][j2] = __builtin_amdgcn_mfma_f32_16x16x32_bf16(afr[i], bfr[j2], acc[i][j2], 0, 0, 0);
    }
  };

  stageA(0, 0);
  issueB(0, 0);
  __syncthreads();

  int buf = 0;
  for (int t = 0; t < 48; ++t) {
    if (t < 47) { stageA(t + 1, buf ^ 1); issueB(t + 1, buf ^ 1); }
    computeT(buf);
    __syncthreads();
    buf ^= 1;
  }

  #pragma unroll
  for (int j2 = 0; j2 < 8; ++j2) {
    int n = oc0 + j2 * 16 + ln15;
    float bv = bias[n];
    #pragma unroll
    for (int i = 0; i < 4; ++i) {
      int mrow = mt * 256 + w * 64 + i * 16 + kgrp * 4;
      #pragma unroll
      for (int r = 0; r < 4; ++r) {
        float v = fmaxf(acc[i][j2][r] + bv, 0.0f);
        xbf[(size_t)(mrow + r) * 512 + n] = f2bf(v);
      }
    }
  }
}

// --------------------------- conv fallback (fp32 A reg-staged) ---------------------------
__global__ __launch_bounds__(256) void conv3x3_mfma_fb_kernel(
    const float* __restrict__ feat, const ushortT* __restrict__ Wt,
    const float* __restrict__ bias, ushortT* __restrict__ xbf) {
  __shared__ __align__(16) char smem[2][32768];
  const int tid = threadIdx.x;
  const int lane = tid & 63;
  const int w = tid >> 6;
  const int kgrp = lane >> 4;
  const int ln15 = lane & 15;
  const int wm = (w >> 1) * 64;
  const int wn = (w & 1) * 64;
  const int wn16 = wn >> 4;
  const int lin = blockIdx.x + 4 * blockIdx.y;
  const int swz = (lin & 7) * 128 + (lin >> 3);
  const int oc0 = (swz & 3) * 128;
  const int mb = swz >> 2;
  const int b = mb >> 5;
  const int y0 = (mb & 31) * 2;
  const int sp0 = (tid >> 6) * 16 + (tid & 15);
  const int sk0 = ((tid >> 4) & 3) * 8;
  const int bn15 = lane & 15;
  const int bic = ((lane >> 4) & 3) * 8;

  f32x4 acc[4][4];
  #pragma unroll
  for (int i = 0; i < 4; ++i)
    #pragma unroll
    for (int j = 0; j < 4; ++j) acc[i][j] = (f32x4){0.f, 0.f, 0.f, 0.f};
  const short8 zv = (short8){0, 0, 0, 0, 0, 0, 0, 0};

  auto issueA = [&](int t, float4* aL) {
    int ic0 = (t / 3) * 32;
    int dy = (t % 3) - 1;
    #pragma unroll
    for (int h = 0; h < 2; ++h) {
      int p = sp0 + h * 64;
      int ys = y0 + (p >> 6) + dy;
      ys = ys < 0 ? 0 : (ys > 63 ? 63 : ys);
      const float* sp = feat + ((size_t)((b * 64 + ys) * 64 + (p & 63))) * 512 + ic0 + sk0;
      aL[h * 2 + 0] = *(const float4*)sp;
      aL[h * 2 + 1] = *(const float4*)(sp + 4);
    }
  };
  auto issueB = [&](int t, int bsel) {
    int ic0 = (t / 3) * 32;
    int ky = t % 3;
    char* Bb = smem[bsel] + 8192;
    #pragma unroll
    for (int i = 0; i < 6; ++i) {
      int c = w + i * 4;
      int kxr = c >> 3, cc = c & 7;
      int kk = ky * 3 + kxr;
      int n = cc * 16 + bn15;
      const ushortT* src = Wt + ((size_t)(kk * 512 + oc0 + n)) * 512 + ic0 + bic;
      gld_lds16(src, Bb + kxr * 8192 + cc * 1024);
    }
  };
  auto writeA = [&](const float4* aL, int bsel) {
    char* Ab = smem[bsel];
    #pragma unroll
    for (int h = 0; h < 2; ++h) {
      float4 f0 = aL[h * 2 + 0], f1 = aL[h * 2 + 1];
      short8 o;
      o[0] = (short)f2bf(f0.x); o[1] = (short)f2bf(f0.y);
      o[2] = (short)f2bf(f0.z); o[3] = (short)f2bf(f0.w);
      o[4] = (short)f2bf(f1.x); o[5] = (short)f2bf(f1.y);
      o[6] = (short)f2bf(f1.z); o[7] = (short)f2bf(f1.w);
      *(short8*)(Ab + h * 4096 + tid * 16) = o;
    }
  };
  auto computeT = [&](int t, int bsel) {
    const char* Ab = smem[bsel];
    const char* Bb = smem[bsel] + 8192;
    int dy = (t % 3) - 1;
    int rowv = y0 + (wm >> 6) + dy;
    if ((unsigned)rowv >= 64u) return;
    #pragma unroll
    for (int kx = 0; kx < 3; ++kx) {
      const int dx = kx - 1;
      short8 bfr[4];
      #pragma unroll
      for (int j = 0; j < 4; ++j)
        bfr[j] = *(const short8*)(Bb + kx * 8192 + (wn16 + j) * 1024 + kgrp * 256 + ln15 * 16);
      short8 afr[4];
      #pragma unroll
      for (int i = 0; i < 4; ++i) {
        int xin = i * 16 + ln15 + dx;
        bool ok = (unsigned)xin < 64u;
        int p_in = wm + (ok ? xin : 0);
        short8 v = *(const short8*)(Ab + (p_in >> 4) * 1024 + kgrp * 256 + (p_in & 15) * 16);
        afr[i] = ok ? v : zv;
      }
      #pragma unroll
      for (int i = 0; i < 4; ++i)
        #pragma unroll
        for (int j = 0; j < 4; ++j)
          acc[i][j] = __builtin_amdgcn_mfma_f32_16x16x32_bf16(afr[i], bfr[j], acc[i][j], 0, 0, 0);
    }
  };

  {
    float4 aL[4];
    issueA(0, aL);
    issueB(0, 0);
    writeA(aL, 0);
  }
  __syncthreads();

  int buf = 0;
  for (int t = 0; t < 48; ++t) {
    float4 aN[4];
    if (t < 47) { issueA(t + 1, aN); issueB(t + 1, buf ^ 1); }
    computeT(t, buf);
    if (t < 47) writeA(aN, buf ^ 1);
    __syncthreads();
    buf ^= 1;
  }

  #pragma unroll
  for (int j = 0; j < 4; ++j) {
    int n = oc0 + wn + j * 16 + ln15;
    float bv = bias[n];
    #pragma unroll
    for (int i = 0; i < 4; ++i) {
      int mrow = mb * 128 + wm + i * 16 + kgrp * 4;
      #pragma unroll
      for (int r = 0; r < 4; ++r) {
        float v = fmaxf(acc[i][j][r] + bv, 0.0f);
        xbf[(size_t)(mrow + r) * 512 + n] = f2bf(v);
      }
    }
  }
}

// --------------------------- heads: bf16 MFMA, 256px/block, XCD-affine ---------------------------
// grid 128: swz = (lin&7)*16 + (lin>>3) -> XCD k owns image k (4096 px).
// Wave w owns 64px x 144 cols: 4 A frags, 9 B frags, 36 MFMA/step, 16 steps.
__global__ __launch_bounds__(256) void heads_mfma_kernel(
    const ushortT* __restrict__ x, const ushortT* __restrict__ Wh,
    const float* __restrict__ bias_all,
    float* __restrict__ out_deltas, float* __restrict__ out_scores, float* __restrict__ out_lmk) {
  __shared__ __align__(16) char smem[2][25600];   // [buf][ A 16KB | B 9KB ]
  const int tid = threadIdx.x;
  const int lane = tid & 63;
  const int w = tid >> 6;
  const int kgrp = lane >> 4;
  const int ln15 = lane & 15;
  const int lin = blockIdx.x;                    // 128 blocks
  const int swz = (lin & 7) * 16 + (lin >> 3);
  const int m0 = swz * 256;
  const int bn15 = lane & 15;
  const int bic = ((lane >> 4) & 3) * 8;

  f32x4 acc[4][9];
  #pragma unroll
  for (int i = 0; i < 4; ++i)
    #pragma unroll
    for (int j = 0; j < 9; ++j) acc[i][j] = (f32x4){0.f, 0.f, 0.f, 0.f};

  auto stage = [&](int t, int bsel) {
    int k0 = t * 32;
    char* Ab = smem[bsel];
    char* Bb = smem[bsel] + 16384;
    #pragma unroll
    for (int i = 0; i < 4; ++i) {
      int cc = w + i * 4;                  // 16 px-chunks over 4 waves
      int p = cc * 16 + bn15;
      gld_lds16(x + ((size_t)(m0 + p)) * 512 + k0 + bic, Ab + cc * 1024);
    }
    for (int c = w; c < 9; c += 4) {
      int n = c * 16 + bn15;
      gld_lds16(Wh + ((size_t)n) * 512 + k0 + bic, Bb + c * 1024);
    }
  };
  auto computeH = [&](int bsel) {
    const char* Ab = smem[bsel] + w * 4096;   // wave's 4 px-chunks
    const char* Bb = smem[bsel] + 16384;
    short8 afr[4], bfr[9];
    #pragma unroll
    for (int i = 0; i < 4; ++i)
      afr[i] = *(const short8*)(Ab + i * 1024 + kgrp * 256 + ln15 * 16);
    #pragma unroll
    for (int j = 0; j < 9; ++j)
      bfr[j] = *(const short8*)(Bb + j * 1024 + kgrp * 256 + ln15 * 16);
    #pragma unroll
    for (int i = 0; i < 4; ++i)
      #pragma unroll
      for (int j = 0; j < 9; ++j)
        acc[i][j] = __builtin_amdgcn_mfma_f32_16x16x32_bf16(afr[i], bfr[j], acc[i][j], 0, 0, 0);
  };

  stage(0, 0);
  __syncthreads();
  int buf = 0;
  for (int t = 0; t < 16; ++t) {
    if (t < 15) stage(t + 1, buf ^ 1);
    computeH(buf);
    __syncthreads();
    buf ^= 1;
  }

  #pragma unroll
  for (int j = 0; j < 9; ++j) {
    int c = j * 16 + ln15;
    float bv = bias_all[c];
    #pragma unroll
    for (int i = 0; i < 4; ++i) {
      int mrow = m0 + w * 64 + i * 16 + kgrp * 4;
      #pragma unroll
      for (int r = 0; r < 4; ++r) {
        size_t m = (size_t)(mrow + r);
        float v = acc[i][j][r] + bv;
        if (c < 72) out_deltas[m * 72 + c] = v;
        else if (c < 81) out_scores[m * 9 + (c - 72)] = 1.0f / (1.0f + expf(-v));
        else if (c < 135) out_lmk[m * 54 + (c - 81)] = v;
      }
    }
  }
}

// --------------------------- launch ---------------------------
extern "C" void kernel_launch(void* const* d_in, const int* in_sizes, int n_in,
                              void* d_out, int out_size, void* d_ws, size_t ws_size,
                              hipStream_t stream) {
  const float* feat    = (const float*)d_in[0];
  const float* gtr     = (const float*)d_in[1];
  const float* conv1_w = (const float*)d_in[2];
  const float* conv1_b = (const float*)d_in[3];
  const float* reg_w   = (const float*)d_in[4];
  const float* reg_b   = (const float*)d_in[5];
  const float* cls_w   = (const float*)d_in[6];
  const float* cls_b   = (const float*)d_in[7];
  const float* lmk_w   = (const float*)d_in[8];
  const float* lmk_b   = (const float*)d_in[9];
  const int*   pih     = (const int*)d_in[10];
  const int*   piw     = (const int*)d_in[11];

  float* out = (float*)d_out;
  float* deltas = out;                       // (8,64,64,72)
  float* scores = out + 2359296;             // (8,64,64,9)
  float* lmk    = out + 2654208;             // (8,64,64,54)
  float* labels = out + 4423680;             // (36864,)
  float* offs   = out + 4460544;             // (36864,4)

  // ws layout (bytes):
  //   Wt bf16        [0,        4718592)
  //   Wh bf16        [4718592,  4866048)
  //   bias_all f32   [4866048,  4866624)
  //   gtbest u32[6]  [4866688,  4866712)
  //   Tsel  u64[2]   [4866752,  4866768)
  //   xbf bf16       [4866816, 38421248)
  //   L    u32       [38421248,38568704)
  //   featbf bf16    [38568704,72123136)   (only if ws_size permits)
  //   zrow bf16      [72123136,72188672)
  ushortT*  Wt          = (ushortT*)d_ws;
  ushortT*  Wh          = (ushortT*)((char*)d_ws + 4718592);
  float*    bias_all    = (float*)((char*)d_ws + 4866048);
  uint32_t* gtbest_bits = (uint32_t*)((char*)d_ws + 4866688);
  unsigned long long* Tsel = (unsigned long long*)((char*)d_ws + 4866752);
  ushortT*  xbf         = (ushortT*)((char*)d_ws + 4866816);
  uint32_t* L           = (uint32_t*)((char*)d_ws + 38421248);
  ushortT*  featbf      = (ushortT*)((char*)d_ws + 38568704);
  ushortT*  zrow        = (ushortT*)((char*)d_ws + 72123136);

  const bool use_bf16A = ws_size >= 72188672ull;

  prep_all_kernel<<<8192, 256, 0, stream>>>(conv1_w, feat, reg_w, cls_w, lmk_w,
                                            reg_b, cls_b, lmk_b, Wt, featbf, zrow,
                                            Wh, bias_all, gtbest_bits,
                                            use_bf16A ? 1 : 0);

  if (use_bf16A) {
    dim3 gconv(2, 256);
    conv3x3_mfma_kernel<<<gconv, 256, 0, stream>>>(featbf, zrow, Wt, conv1_b, xbf);
  } else {
    dim3 gconv(4, 256);
    conv3x3_mfma_fb_kernel<<<gconv, 256, 0, stream>>>(feat, Wt, conv1_b, xbf);
  }

  heads_mfma_kernel<<<128, 256, 0, stream>>>(xbf, Wh, bias_all, deltas, scores, lmk);

  labels_gtmax_kernel<<<144, 256, 0, stream>>>(gtr, pih, piw, gtbest_bits);
  labels_code_kernel<<<144, 256, 0, stream>>>(gtr, pih, piw, gtbest_bits, L);
  labels_select_kernel<<<1, 1024, 0, stream>>>(L, Tsel);
  labels_final_kernel<<<144, 256, 0, stream>>>(L, Tsel, gtr, pih, piw, labels, offs);
}

// Round 15
// 221.905 us; speedup vs baseline: 1.0283x; 1.0283x over previous
//
#include <hip/hip_runtime.h>
#include <cstdint>
#include <cstddef>

// ---------------------------------------------------------------------------
// RPN_11562051961518 — r15: exact revert to r13 (measured best, 222.1us).
// conv: 256px x 128oc tile, 4 waves x (64px x 128oc), ratio 2.67, 2 blk/CU,
// all-gld_lds staging, prefetch-before-compute, one barrier/step, XCD swizzle.
// prep: separate coalesced Wt transpose + misc. heads: 256 blocks x 128px.
// labels: bit-exact threefry + histogram rank-select pipeline.
// ---------------------------------------------------------------------------

#define A_TOT 36864

typedef unsigned short ushortT;
typedef __attribute__((ext_vector_type(8))) short short8;
typedef __attribute__((ext_vector_type(4))) float f32x4;

typedef __attribute__((address_space(1))) unsigned char gbyte_t;
typedef __attribute__((address_space(3))) unsigned char lbyte_t;

__device__ __forceinline__ void gld_lds16(const void* g, void* l) {
  __builtin_amdgcn_global_load_lds((gbyte_t*)g, (lbyte_t*)l, 16, 0, 0);
}

__device__ __forceinline__ uint32_t rotl32(uint32_t v, int d) { return (v << d) | (v >> (32 - d)); }

__device__ __forceinline__ ushortT f2bf(float f) {
  uint32_t u = __float_as_uint(f);
  uint32_t r = (u + 0x7FFFu + ((u >> 16) & 1u)) >> 16;   // RNE
  return (ushortT)r;
}

__device__ __forceinline__ uint32_t f2mono(float f) {
  uint32_t b = __float_as_uint(f);
  return b ^ ((b >> 31) ? 0xFFFFFFFFu : 0x80000000u);
}
__device__ __forceinline__ float mono2f(uint32_t u) {
  uint32_t b = (u >> 31) ? (u ^ 0x80000000u) : ~u;
  return __uint_as_float(b);
}

// JAX threefry2x32, key=(0,42), partitionable: counter (0, i), out = x0^x1.
__device__ uint32_t threefry_bits_for(uint32_t a) {
  uint32_t x0 = 0u, x1 = a;
  const uint32_t k0 = 0u, k1 = 42u;
  const uint32_t k2 = k0 ^ k1 ^ 0x1BD11BDAu;
  x0 += k0; x1 += k1;
#define TF_RND(r) { x0 += x1; x1 = rotl32(x1, (r)); x1 ^= x0; }
  TF_RND(13) TF_RND(15) TF_RND(26) TF_RND(6)
  x0 += k1; x1 += k2 + 1u;
  TF_RND(17) TF_RND(29) TF_RND(16) TF_RND(24)
  x0 += k2; x1 += k0 + 2u;
  TF_RND(13) TF_RND(15) TF_RND(26) TF_RND(6)
  x0 += k0; x1 += k1 + 3u;
  TF_RND(17) TF_RND(29) TF_RND(16) TF_RND(24)
  x0 += k1; x1 += k2 + 4u;
  TF_RND(13) TF_RND(15) TF_RND(26) TF_RND(6)
  x0 += k2; x1 += k0 + 5u;
#undef TF_RND
  return x0 ^ x1;
}

struct Anc { float x1, y1, x2, y2; bool inside; };

__device__ __forceinline__ Anc anchor_at(int a, float iw, float ih) {
  Anc A;
  {
    #pragma clang fp contract(off)
    int p = a / 9;
    int q = a - p * 9;
    int i = p >> 6;
    int j = p & 63;
    int ri = q / 3;
    int si = q - ri * 3;
    const float ratios[3] = {0.5f, 1.0f, 2.0f};
    const float scales[3] = {8.0f, 16.0f, 32.0f};
    float xs = iw / 64.0f;
    float ys = ih / 64.0f;
    float cx = ((float)i + 0.5f) * xs;
    float cy = ((float)j + 0.5f) * ys;
    float r = ratios[ri], s = scales[si];
    float h = sqrtf((s * s) / r) * ys;
    float w = h * r * xs / ys;
    A.x1 = cx - w * 0.5f;
    A.y1 = cy - h * 0.5f;
    A.x2 = cx + w * 0.5f;
    A.y2 = cy + h * 0.5f;
    A.inside = (A.x1 >= 0.0f) && (A.y1 >= 0.0f) && (A.x2 <= iw) && (A.y2 <= ih);
  }
  return A;
}

__device__ __forceinline__ float iou_one(const Anc& A, const float* g) {
  #pragma clang fp contract(off)
  float x1 = fmaxf(A.x1, g[0]);
  float y1 = fmaxf(A.y1, g[1]);
  float x2 = fminf(A.x2, g[2]);
  float y2 = fminf(A.y2, g[3]);
  float inter = fmaxf(x2 - x1, 0.0f) * fmaxf(y2 - y1, 0.0f);
  float area_a = (A.x2 - A.x1) * (A.y2 - A.y1);
  float area_g = (g[2] - g[0]) * (g[3] - g[1]);
  float un = (area_a + area_g) - inter;
  return inter > 0.0f ? (inter / un) : 0.0f;
}

// --------------------------- labels pipeline ---------------------------
__global__ __launch_bounds__(256) void labels_gtmax_kernel(
    const float* __restrict__ gtr, const int* __restrict__ pih, const int* __restrict__ piw,
    uint32_t* __restrict__ gtbest_bits) {
  __shared__ float s_gt[6][4];
  __shared__ float s_red[4][6];
  int tid = threadIdx.x;
  if (tid < 24) ((float*)s_gt)[tid] = gtr[8 + tid];
  __syncthreads();
  float iw = (float)piw[0], ih = (float)pih[0];
  int a = blockIdx.x * 256 + tid;
  Anc A = anchor_at(a, iw, ih);
  int w = tid >> 6;
  #pragma unroll
  for (int g = 0; g < 6; ++g) {
    float v = A.inside ? iou_one(A, s_gt[g]) : -1.0f;
    for (int off = 32; off > 0; off >>= 1) v = fmaxf(v, __shfl_down(v, off, 64));
    if ((tid & 63) == 0) s_red[w][g] = v;
  }
  __syncthreads();
  if (tid < 6) {
    float m = fmaxf(fmaxf(s_red[0][tid], s_red[1][tid]), fmaxf(s_red[2][tid], s_red[3][tid]));
    atomicMax(&gtbest_bits[tid], f2mono(m));
  }
}

__global__ __launch_bounds__(256) void labels_code_kernel(
    const float* __restrict__ gtr, const int* __restrict__ pih, const int* __restrict__ piw,
    const uint32_t* __restrict__ gtbest_bits, uint32_t* __restrict__ L) {
  __shared__ float s_gt[6][4];
  __shared__ float s_gb[6];
  int tid = threadIdx.x;
  if (tid < 24) ((float*)s_gt)[tid] = gtr[8 + tid];
  if (tid < 6) s_gb[tid] = mono2f(gtbest_bits[tid]);
  __syncthreads();
  float iw = (float)piw[0], ih = (float)pih[0];
  int a = blockIdx.x * 256 + tid;
  Anc A = anchor_at(a, iw, ih);
  uint32_t code;
  if (!A.inside) {
    code = 2u;
  } else {
    float best = -1.0f;
    bool isb = false;
    #pragma unroll
    for (int g = 0; g < 6; ++g) {
      float v = iou_one(A, s_gt[g]);
      best = fmaxf(best, v);
      if (v == s_gb[g] && s_gb[g] > -1.0f) isb = true;
    }
    code = (best >= 0.5f || isb) ? 1u : 0u;
  }
  uint32_t m = threefry_bits_for((uint32_t)a) >> 9;
  L[a] = (m << 2) | code;
}

__global__ __launch_bounds__(1024) void labels_select_kernel(
    const uint32_t* __restrict__ L, unsigned long long* __restrict__ Tsel) {
  __shared__ int hist[2][512];
  __shared__ unsigned long long list[2][512];
  __shared__ int lcnt[2];
  __shared__ int s_b[2], s_r[2];
  int tid = threadIdx.x;
  hist[tid >> 9][tid & 511] = 0;
  if (tid < 2) lcnt[tid] = 0;
  __syncthreads();
  for (int a = tid; a < A_TOT; a += 1024) {
    uint32_t v = L[a];
    uint32_t c = v & 3u;
    if (c < 2u) atomicAdd(&hist[c][v >> 16], 1);
  }
  __syncthreads();
  if (tid < 2) {
    int need = (tid == 1) ? 10 : 22;
    int tot = 0;
    for (int i = 0; i < 512; ++i) tot += hist[tid][i];
    int b = -1, r = 0, cum = 0;
    if (tot > need) {
      for (int i = 0; i < 512; ++i) {
        if (cum + hist[tid][i] >= need) { b = i; r = need - cum; break; }
        cum += hist[tid][i];
      }
    }
    s_b[tid] = b; s_r[tid] = r;
    if (b < 0) Tsel[tid] = ~0ull;
  }
  __syncthreads();
  for (int a = tid; a < A_TOT; a += 1024) {
    uint32_t v = L[a];
    uint32_t c = v & 3u;
    if (c < 2u && s_b[c] == (int)(v >> 16)) {
      int idx = atomicAdd(&lcnt[c], 1);
      if (idx < 512) list[c][idx] = (((unsigned long long)(v >> 2)) << 16) | (unsigned)a;
    }
  }
  __syncthreads();
  #pragma unroll
  for (int c = 0; c < 2; ++c) {
    if (s_b[c] < 0) continue;
    int n = lcnt[c] < 512 ? lcnt[c] : 512;
    if (tid < n) {
      unsigned long long k = list[c][tid];
      int rank = 1;
      for (int i = 0; i < n; ++i) rank += (list[c][i] < k) ? 1 : 0;
      if (rank == s_r[c]) Tsel[c] = k;
    }
  }
}

__global__ __launch_bounds__(256) void labels_final_kernel(
    const uint32_t* __restrict__ L, const unsigned long long* __restrict__ Tsel,
    const float* __restrict__ gtr, const int* __restrict__ pih, const int* __restrict__ piw,
    float* __restrict__ labels_out, float* __restrict__ offs_out) {
  __shared__ float s_gt[6][4];
  int tid = threadIdx.x;
  if (tid < 24) ((float*)s_gt)[tid] = gtr[8 + tid];
  __syncthreads();
  float iw = (float)piw[0], ih = (float)pih[0];
  int a = blockIdx.x * 256 + tid;
  uint32_t v = L[a];
  uint32_t code = v & 3u;
  unsigned long long K = (((unsigned long long)(v >> 2)) << 16) | (unsigned)a;
  bool pos = (code == 1u) && (K <= Tsel[1]);
  bool neg = (code == 0u) && (K <= Tsel[0]);
  labels_out[a] = pos ? 1.0f : (neg ? 0.0f : -1.0f);
  float o0 = 0.0f, o1 = 0.0f, o2 = 0.0f, o3 = 0.0f;
  if (pos) {
    #pragma clang fp contract(off)
    Anc A = anchor_at(a, iw, ih);
    int bi = 0;
    float bv = iou_one(A, s_gt[0]);
    for (int g = 1; g < 6; ++g) {
      float vg = iou_one(A, s_gt[g]);
      if (vg > bv) { bv = vg; bi = g; }
    }
    const float eps = 1.1920928955078125e-07f;
    float wa = fmaxf(A.x2 - A.x1, eps);
    float ha = fmaxf(A.y2 - A.y1, eps);
    float xa = A.x1 + wa * 0.5f;
    float ya = A.y1 + ha * 0.5f;
    const float* g = s_gt[bi];
    float wg = g[2] - g[0];
    float hg = g[3] - g[1];
    float xg = g[0] + wg * 0.5f;
    float yg = g[1] + hg * 0.5f;
    o0 = (xg - xa) / wa;
    o1 = (yg - ya) / ha;
    o2 = logf(wg / wa);
    o3 = logf(hg / ha);
  }
  offs_out[a * 4 + 0] = o0;
  offs_out[a * 4 + 1] = o1;
  offs_out[a * 4 + 2] = o2;
  offs_out[a * 4 + 3] = o3;
}

// --------------------------- prep: coalesced Wt transpose ---------------------------
__global__ __launch_bounds__(256) void prep_wt_kernel(
    const float* __restrict__ w, ushortT* __restrict__ Wt) {
  __shared__ float tile[64][65];
  int blk = blockIdx.x;
  int kk = blk / 64;
  int rem = blk - kk * 64;
  int ic0 = (rem >> 3) * 64;
  int oc0 = (rem & 7) * 64;
  int t = threadIdx.x;
  int tr = t >> 6;
  int tc = t & 63;
  #pragma unroll
  for (int r = 0; r < 16; ++r) {
    int ic = tr * 16 + r;
    tile[ic][tc] = w[((size_t)(kk * 512 + ic0 + ic)) * 512 + oc0 + tc];
  }
  __syncthreads();
  #pragma unroll
  for (int r = 0; r < 16; ++r) {
    int oc = tr * 16 + r;
    Wt[((size_t)(kk * 512 + oc0 + oc)) * 512 + ic0 + tc] = f2bf(tile[tc][oc]);
  }
}

// --------------------------- prep: feat cast + small tables ---------------------------
__global__ void prep_misc_kernel(const float* __restrict__ feat,
                                 const float* __restrict__ reg_w, const float* __restrict__ cls_w,
                                 const float* __restrict__ lmk_w, const float* __restrict__ reg_b,
                                 const float* __restrict__ cls_b, const float* __restrict__ lmk_b,
                                 ushortT* __restrict__ featbf, ushortT* __restrict__ zrow,
                                 ushortT* __restrict__ Wh, float* __restrict__ bias_all,
                                 uint32_t* __restrict__ gtbest_bits, int do_feat) {
  int idx = blockIdx.x * 256 + threadIdx.x;
  if (do_feat) {
    const float4 f0 = *(const float4*)(feat + (size_t)idx * 8);
    const float4 f1 = *(const float4*)(feat + (size_t)idx * 8 + 4);
    short8 o;
    o[0] = (short)f2bf(f0.x); o[1] = (short)f2bf(f0.y);
    o[2] = (short)f2bf(f0.z); o[3] = (short)f2bf(f0.w);
    o[4] = (short)f2bf(f1.x); o[5] = (short)f2bf(f1.y);
    o[6] = (short)f2bf(f1.z); o[7] = (short)f2bf(f1.w);
    *(short8*)(featbf + (size_t)idx * 8) = o;
  }
  if (idx < 73728) {
    int c = idx >> 9, ic = idx & 511;
    float v = 0.0f;
    if (c < 72) v = reg_w[ic * 72 + c];
    else if (c < 81) v = cls_w[ic * 9 + (c - 72)];
    else if (c < 135) v = lmk_w[ic * 54 + (c - 81)];
    Wh[idx] = f2bf(v);
  }
  if (do_feat && idx < 4096) {
    *(short8*)(zrow + (size_t)idx * 8) = (short8){0, 0, 0, 0, 0, 0, 0, 0};
  }
  if (idx < 144) {
    float bv = 0.0f;
    if (idx < 72) bv = reg_b[idx];
    else if (idx < 81) bv = cls_b[idx - 72];
    else if (idx < 135) bv = lmk_b[idx - 81];
    bias_all[idx] = bv;
  }
  if (idx < 6) gtbest_bits[idx] = f2mono(-1.0f);
}

// --------------------------- conv3x3 bf16 MFMA: 256px x 128oc tile (r13) ---------------------------
__global__ __launch_bounds__(256, 2) void conv3x3_mfma_kernel(
    const ushortT* __restrict__ featbf, const ushortT* __restrict__ zrow,
    const ushortT* __restrict__ Wt, const float* __restrict__ bias,
    ushortT* __restrict__ xbf) {
  __shared__ __align__(16) char Asm[2][16384];   // [buf][4 row-slots][4 grp x 1KB]
  __shared__ __align__(16) char Bsm[2][24576];   // [buf][3 kx][8 oc-frag x 1KB]
  const int tid = threadIdx.x;
  const int lane = tid & 63;
  const int w = tid >> 6;          // wave 0..3 = row slot
  const int kgrp = lane >> 4;
  const int ln15 = lane & 15;

  const int lin = blockIdx.x + 2 * blockIdx.y;
  const int swz = (lin & 7) * 64 + (lin >> 3);
  const int j = swz & 63;
  const int xcd = swz >> 6;
  const int oc0 = (j >> 4) * 128;
  const int mt = xcd * 16 + (j & 15);   // m-tile 0..127
  const int b = mt >> 4;
  const int y0 = (mt & 15) * 4;

  const int bn15 = lane & 15;
  const int bic = ((lane >> 4) & 3) * 8;

  f32x4 acc[4][8];
  #pragma unroll
  for (int i = 0; i < 4; ++i)
    #pragma unroll
    for (int j2 = 0; j2 < 8; ++j2) acc[i][j2] = (f32x4){0.f, 0.f, 0.f, 0.f};
  const short8 zv = (short8){0, 0, 0, 0, 0, 0, 0, 0};

  auto stageA = [&](int t, int bsel) {
    int ic0 = (t / 3) * 32;
    int dy = (t % 3) - 1;
    char* Ab = Asm[bsel];
    #pragma unroll
    for (int i = 0; i < 4; ++i) {
      int c = w + i * 4;
      int s = c >> 2, q = c & 3;
      int ysrc = y0 + s + dy;
      bool vy = (unsigned)ysrc < 64u;
      const ushortT* rowbase = vy ? (featbf + ((size_t)((b * 64 + ysrc) * 64)) * 512) : zrow;
      const ushortT* src = rowbase + (size_t)(q * 16 + bn15) * 512 + ic0 + bic;
      gld_lds16(src, Ab + s * 4096 + q * 1024);
    }
  };
  auto issueB = [&](int t, int bsel) {
    int ic0 = (t / 3) * 32;
    int ky = t % 3;
    char* Bb = Bsm[bsel];
    #pragma unroll
    for (int i = 0; i < 6; ++i) {
      int c = w + i * 4;
      int kxr = c >> 3, cc = c & 7;
      int kk = ky * 3 + kxr;
      int n = cc * 16 + bn15;
      const ushortT* src = Wt + ((size_t)(kk * 512 + oc0 + n)) * 512 + ic0 + bic;
      gld_lds16(src, Bb + kxr * 8192 + cc * 1024);
    }
  };
  auto computeT = [&](int bsel) {
    const char* Ab = Asm[bsel] + w * 4096;   // wave's row slot (OOB rows are zero)
    const char* Bb = Bsm[bsel];
    #pragma unroll
    for (int kx = 0; kx < 3; ++kx) {
      const int dx = kx - 1;
      short8 bfr[8];
      #pragma unroll
      for (int j2 = 0; j2 < 8; ++j2)
        bfr[j2] = *(const short8*)(Bb + kx * 8192 + j2 * 1024 + kgrp * 256 + ln15 * 16);
      short8 afr[4];
      #pragma unroll
      for (int i = 0; i < 4; ++i) {
        int xin = i * 16 + ln15 + dx;
        bool ok = (unsigned)xin < 64u;
        int p = ok ? xin : 0;
        short8 v = *(const short8*)(Ab + (p >> 4) * 1024 + kgrp * 256 + (p & 15) * 16);
        afr[i] = ok ? v : zv;
      }
      #pragma unroll
      for (int i = 0; i < 4; ++i)
        #pragma unroll
        for (int j2 = 0; j2 < 8; ++j2)
          acc[i][j2] = __builtin_amdgcn_mfma_f32_16x16x32_bf16(afr[i], bfr[j2], acc[i][j2], 0, 0, 0);
    }
  };

  stageA(0, 0);
  issueB(0, 0);
  __syncthreads();

  int buf = 0;
  for (int t = 0; t < 48; ++t) {
    if (t < 47) { stageA(t + 1, buf ^ 1); issueB(t + 1, buf ^ 1); }
    computeT(buf);
    __syncthreads();
    buf ^= 1;
  }

  #pragma unroll
  for (int j2 = 0; j2 < 8; ++j2) {
    int n = oc0 + j2 * 16 + ln15;
    float bv = bias[n];
    #pragma unroll
    for (int i = 0; i < 4; ++i) {
      int mrow = mt * 256 + w * 64 + i * 16 + kgrp * 4;
      #pragma unroll
      for (int r = 0; r < 4; ++r) {
        float v = fmaxf(acc[i][j2][r] + bv, 0.0f);
        xbf[(size_t)(mrow + r) * 512 + n] = f2bf(v);
      }
    }
  }
}

// --------------------------- conv fallback (fp32 A reg-staged, r6 geometry) ---------------------------
__global__ __launch_bounds__(256) void conv3x3_mfma_fb_kernel(
    const float* __restrict__ feat, const ushortT* __restrict__ Wt,
    const float* __restrict__ bias, ushortT* __restrict__ xbf) {
  __shared__ __align__(16) char smem[2][32768];
  const int tid = threadIdx.x;
  const int lane = tid & 63;
  const int w = tid >> 6;
  const int kgrp = lane >> 4;
  const int ln15 = lane & 15;
  const int wm = (w >> 1) * 64;
  const int wn = (w & 1) * 64;
  const int wn16 = wn >> 4;
  const int lin = blockIdx.x + 4 * blockIdx.y;
  const int swz = (lin & 7) * 128 + (lin >> 3);
  const int oc0 = (swz & 3) * 128;
  const int mb = swz >> 2;
  const int b = mb >> 5;
  const int y0 = (mb & 31) * 2;
  const int sp0 = (tid >> 6) * 16 + (tid & 15);
  const int sk0 = ((tid >> 4) & 3) * 8;
  const int bn15 = lane & 15;
  const int bic = ((lane >> 4) & 3) * 8;

  f32x4 acc[4][4];
  #pragma unroll
  for (int i = 0; i < 4; ++i)
    #pragma unroll
    for (int j = 0; j < 4; ++j) acc[i][j] = (f32x4){0.f, 0.f, 0.f, 0.f};
  const short8 zv = (short8){0, 0, 0, 0, 0, 0, 0, 0};

  auto issueA = [&](int t, float4* aL) {
    int ic0 = (t / 3) * 32;
    int dy = (t % 3) - 1;
    #pragma unroll
    for (int h = 0; h < 2; ++h) {
      int p = sp0 + h * 64;
      int ys = y0 + (p >> 6) + dy;
      ys = ys < 0 ? 0 : (ys > 63 ? 63 : ys);
      const float* sp = feat + ((size_t)((b * 64 + ys) * 64 + (p & 63))) * 512 + ic0 + sk0;
      aL[h * 2 + 0] = *(const float4*)sp;
      aL[h * 2 + 1] = *(const float4*)(sp + 4);
    }
  };
  auto issueB = [&](int t, int bsel) {
    int ic0 = (t / 3) * 32;
    int ky = t % 3;
    char* Bb = smem[bsel] + 8192;
    #pragma unroll
    for (int i = 0; i < 6; ++i) {
      int c = w + i * 4;
      int kxr = c >> 3, cc = c & 7;
      int kk = ky * 3 + kxr;
      int n = cc * 16 + bn15;
      const ushortT* src = Wt + ((size_t)(kk * 512 + oc0 + n)) * 512 + ic0 + bic;
      gld_lds16(src, Bb + kxr * 8192 + cc * 1024);
    }
  };
  auto writeA = [&](const float4* aL, int bsel) {
    char* Ab = smem[bsel];
    #pragma unroll
    for (int h = 0; h < 2; ++h) {
      float4 f0 = aL[h * 2 + 0], f1 = aL[h * 2 + 1];
      short8 o;
      o[0] = (short)f2bf(f0.x); o[1] = (short)f2bf(f0.y);
      o[2] = (short)f2bf(f0.z); o[3] = (short)f2bf(f0.w);
      o[4] = (short)f2bf(f1.x); o[5] = (short)f2bf(f1.y);
      o[6] = (short)f2bf(f1.z); o[7] = (short)f2bf(f1.w);
      *(short8*)(Ab + h * 4096 + tid * 16) = o;
    }
  };
  auto computeT = [&](int t, int bsel) {
    const char* Ab = smem[bsel];
    const char* Bb = smem[bsel] + 8192;
    int dy = (t % 3) - 1;
    int rowv = y0 + (wm >> 6) + dy;
    if ((unsigned)rowv >= 64u) return;
    #pragma unroll
    for (int kx = 0; kx < 3; ++kx) {
      const int dx = kx - 1;
      short8 bfr[4];
      #pragma unroll
      for (int j = 0; j < 4; ++j)
        bfr[j] = *(const short8*)(Bb + kx * 8192 + (wn16 + j) * 1024 + kgrp * 256 + ln15 * 16);
      short8 afr[4];
      #pragma unroll
      for (int i = 0; i < 4; ++i) {
        int xin = i * 16 + ln15 + dx;
        bool ok = (unsigned)xin < 64u;
        int p_in = wm + (ok ? xin : 0);
        short8 v = *(const short8*)(Ab + (p_in >> 4) * 1024 + kgrp * 256 + (p_in & 15) * 16);
        afr[i] = ok ? v : zv;
      }
      #pragma unroll
      for (int i = 0; i < 4; ++i)
        #pragma unroll
        for (int j = 0; j < 4; ++j)
          acc[i][j] = __builtin_amdgcn_mfma_f32_16x16x32_bf16(afr[i], bfr[j], acc[i][j], 0, 0, 0);
    }
  };

  {
    float4 aL[4];
    issueA(0, aL);
    issueB(0, 0);
    writeA(aL, 0);
  }
  __syncthreads();

  int buf = 0;
  for (int t = 0; t < 48; ++t) {
    float4 aN[4];
    if (t < 47) { issueA(t + 1, aN); issueB(t + 1, buf ^ 1); }
    computeT(t, buf);
    if (t < 47) writeA(aN, buf ^ 1);
    __syncthreads();
    buf ^= 1;
  }

  #pragma unroll
  for (int j = 0; j < 4; ++j) {
    int n = oc0 + wn + j * 16 + ln15;
    float bv = bias[n];
    #pragma unroll
    for (int i = 0; i < 4; ++i) {
      int mrow = mb * 128 + wm + i * 16 + kgrp * 4;
      #pragma unroll
      for (int r = 0; r < 4; ++r) {
        float v = fmaxf(acc[i][j][r] + bv, 0.0f);
        xbf[(size_t)(mrow + r) * 512 + n] = f2bf(v);
      }
    }
  }
}

// --------------------------- heads: bf16 MFMA, XCD-affine (r13) ---------------------------
__global__ __launch_bounds__(256) void heads_mfma_kernel(
    const ushortT* __restrict__ x, const ushortT* __restrict__ Wh,
    const float* __restrict__ bias_all,
    float* __restrict__ out_deltas, float* __restrict__ out_scores, float* __restrict__ out_lmk) {
  __shared__ __align__(16) char smem[2][17408];   // [buf][ A 8KB | B 9KB ]
  const int tid = threadIdx.x;
  const int lane = tid & 63;
  const int w = tid >> 6;
  const int kgrp = lane >> 4;
  const int ln15 = lane & 15;
  const int lin = blockIdx.x;                    // 256 blocks
  const int swz = (lin & 7) * 32 + (lin >> 3);
  const int m0 = swz * 128;
  const int bn15 = lane & 15;
  const int bic = ((lane >> 4) & 3) * 8;

  f32x4 acc[2][9];
  #pragma unroll
  for (int i = 0; i < 2; ++i)
    #pragma unroll
    for (int j = 0; j < 9; ++j) acc[i][j] = (f32x4){0.f, 0.f, 0.f, 0.f};

  auto stage = [&](int t, int bsel) {
    int k0 = t * 32;
    char* Ab = smem[bsel];
    char* Bb = smem[bsel] + 8192;
    #pragma unroll
    for (int i = 0; i < 2; ++i) {
      int cc = w + i * 4;
      int p = cc * 16 + bn15;
      gld_lds16(x + ((size_t)(m0 + p)) * 512 + k0 + bic, Ab + cc * 1024);
    }
    for (int c = w; c < 9; c += 4) {
      int n = c * 16 + bn15;
      gld_lds16(Wh + ((size_t)n) * 512 + k0 + bic, Bb + c * 1024);
    }
  };
  auto computeH = [&](int bsel) {
    const char* Ab = smem[bsel];
    const char* Bb = smem[bsel] + 8192;
    short8 afr[2], bfr[9];
    #pragma unroll
    for (int i = 0; i < 2; ++i)
      afr[i] = *(const short8*)(Ab + (w * 2 + i) * 1024 + kgrp * 256 + ln15 * 16);
    #pragma unroll
    for (int j = 0; j < 9; ++j)
      bfr[j] = *(const short8*)(Bb + j * 1024 + kgrp * 256 + ln15 * 16);
    #pragma unroll
    for (int i = 0; i < 2; ++i)
      #pragma unroll
      for (int j = 0; j < 9; ++j)
        acc[i][j] = __builtin_amdgcn_mfma_f32_16x16x32_bf16(afr[i], bfr[j], acc[i][j], 0, 0, 0);
  };

  stage(0, 0);
  __syncthreads();
  int buf = 0;
  for (int t = 0; t < 16; ++t) {
    if (t < 15) stage(t + 1, buf ^ 1);
    computeH(buf);
    __syncthreads();
    buf ^= 1;
  }

  #pragma unroll
  for (int j = 0; j < 9; ++j) {
    int c = j * 16 + ln15;
    float bv = bias_all[c];
    #pragma unroll
    for (int i = 0; i < 2; ++i) {
      int mrow = m0 + w * 32 + i * 16 + kgrp * 4;
      #pragma unroll
      for (int r = 0; r < 4; ++r) {
        size_t m = (size_t)(mrow + r);
        float v = acc[i][j][r] + bv;
        if (c < 72) out_deltas[m * 72 + c] = v;
        else if (c < 81) out_scores[m * 9 + (c - 72)] = 1.0f / (1.0f + expf(-v));
        else if (c < 135) out_lmk[m * 54 + (c - 81)] = v;
      }
    }
  }
}

// --------------------------- launch ---------------------------
extern "C" void kernel_launch(void* const* d_in, const int* in_sizes, int n_in,
                              void* d_out, int out_size, void* d_ws, size_t ws_size,
                              hipStream_t stream) {
  const float* feat    = (const float*)d_in[0];
  const float* gtr     = (const float*)d_in[1];
  const float* conv1_w = (const float*)d_in[2];
  const float* conv1_b = (const float*)d_in[3];
  const float* reg_w   = (const float*)d_in[4];
  const float* reg_b   = (const float*)d_in[5];
  const float* cls_w   = (const float*)d_in[6];
  const float* cls_b   = (const float*)d_in[7];
  const float* lmk_w   = (const float*)d_in[8];
  const float* lmk_b   = (const float*)d_in[9];
  const int*   pih     = (const int*)d_in[10];
  const int*   piw     = (const int*)d_in[11];

  float* out = (float*)d_out;
  float* deltas = out;                       // (8,64,64,72)
  float* scores = out + 2359296;             // (8,64,64,9)
  float* lmk    = out + 2654208;             // (8,64,64,54)
  float* labels = out + 4423680;             // (36864,)
  float* offs   = out + 4460544;             // (36864,4)

  // ws layout (bytes):
  //   Wt bf16        [0,        4718592)
  //   Wh bf16        [4718592,  4866048)
  //   bias_all f32   [4866048,  4866624)
  //   gtbest u32[6]  [4866688,  4866712)
  //   Tsel  u64[2]   [4866752,  4866768)
  //   xbf bf16       [4866816, 38421248)
  //   L    u32       [38421248,38568704)
  //   featbf bf16    [38568704,72123136)   (only if ws_size permits)
  //   zrow bf16      [72123136,72188672)
  ushortT*  Wt          = (ushortT*)d_ws;
  ushortT*  Wh          = (ushortT*)((char*)d_ws + 4718592);
  float*    bias_all    = (float*)((char*)d_ws + 4866048);
  uint32_t* gtbest_bits = (uint32_t*)((char*)d_ws + 4866688);
  unsigned long long* Tsel = (unsigned long long*)((char*)d_ws + 4866752);
  ushortT*  xbf         = (ushortT*)((char*)d_ws + 4866816);
  uint32_t* L           = (uint32_t*)((char*)d_ws + 38421248);
  ushortT*  featbf      = (ushortT*)((char*)d_ws + 38568704);
  ushortT*  zrow        = (ushortT*)((char*)d_ws + 72123136);

  const bool use_bf16A = ws_size >= 72188672ull;

  prep_wt_kernel<<<576, 256, 0, stream>>>(conv1_w, Wt);
  prep_misc_kernel<<<8192, 256, 0, stream>>>(feat, reg_w, cls_w, lmk_w,
                                             reg_b, cls_b, lmk_b, featbf, zrow,
                                             Wh, bias_all, gtbest_bits,
                                             use_bf16A ? 1 : 0);

  if (use_bf16A) {
    dim3 gconv(2, 256);
    conv3x3_mfma_kernel<<<gconv, 256, 0, stream>>>(featbf, zrow, Wt, conv1_b, xbf);
  } else {
    dim3 gconv(4, 256);
    conv3x3_mfma_fb_kernel<<<gconv, 256, 0, stream>>>(feat, Wt, conv1_b, xbf);
  }

  heads_mfma_kernel<<<256, 256, 0, stream>>>(xbf, Wh, bias_all, deltas, scores, lmk);

  labels_gtmax_kernel<<<144, 256, 0, stream>>>(gtr, pih, piw, gtbest_bits);
  labels_code_kernel<<<144, 256, 0, stream>>>(gtr, pih, piw, gtbest_bits, L);
  labels_select_kernel<<<1, 1024, 0, stream>>>(L, Tsel);
  labels_final_kernel<<<144, 256, 0, stream>>>(L, Tsel, gtr, pih, piw, labels, offs);
}